// Round 1
// baseline (238.276 us; speedup 1.0000x reference)
//
#include <hip/hip_runtime.h>
#include <float.h>

#define TSEQ 4096
#define CEMB 1024
#define NH 64       // head size
#define WIN 256
#define QT 32
#define KT 64

// ============ QKV projection: [kb|qb|vb] = x @ [Wk|Wq|Wv] ============
// x: [B*T, 1024] fp32; W*: [1024, 64] fp32; outputs [B*T, 64] fp32 in ws.
// grid = M/64 blocks, 256 threads. Cols 0-63 -> K, 64-127 -> Q, 128-191 -> V.
__global__ __launch_bounds__(256)
void qkv_proj(const float* __restrict__ x,
              const float* __restrict__ Wk,
              const float* __restrict__ Wq,
              const float* __restrict__ Wv,
              float* __restrict__ kb,
              float* __restrict__ qb,
              float* __restrict__ vb)
{
    __shared__ float As[2][16][68];    // A^T tile: [k][m], padded (conflict-free b128 reads)
    __shared__ float Bs[2][16][196];   // B tile: [k][n], padded

    const int tid = threadIdx.x;
    const int m0  = blockIdx.x << 6;

    // A load: one float4 per thread: (row = tid>>2, k4 = (tid&3)*4)
    const int arow  = tid >> 2;
    const int ak4   = (tid & 3) << 2;
    const int axoff = (m0 + arow) * CEMB + ak4;

    // B load: 3 float4 per thread over 16x192 tile
    int bkk[3]; int bcol[3]; const float* bw[3];
    #pragma unroll
    for (int i = 0; i < 3; ++i) {
        const int idx = tid + (i << 8);      // f4 index in [0,768)
        bkk[i] = idx / 48;
        const int col = (idx % 48) << 2;
        bcol[i] = col;
        bw[i] = ((col < 64) ? Wk : ((col < 128) ? Wq : Wv)) + (col & 63);
    }

    const int tr = (tid >> 4) << 2;     // 4 output rows
    const int tc = (tid & 15) * 12;     // 12 output cols

    float acc[4][12];
    #pragma unroll
    for (int i = 0; i < 4; ++i)
        #pragma unroll
        for (int j = 0; j < 12; ++j) acc[i][j] = 0.f;

    // prologue: tile 0 -> buffer 0
    float4 ra  = *(const float4*)&x[axoff];
    float4 rb0 = *(const float4*)&bw[0][bkk[0] * NH];
    float4 rb1 = *(const float4*)&bw[1][bkk[1] * NH];
    float4 rb2 = *(const float4*)&bw[2][bkk[2] * NH];
    {
        const float rav[4] = {ra.x, ra.y, ra.z, ra.w};
        #pragma unroll
        for (int j = 0; j < 4; ++j) As[0][ak4 + j][arow] = rav[j];
        *(float4*)&Bs[0][bkk[0]][bcol[0]] = rb0;
        *(float4*)&Bs[0][bkk[1]][bcol[1]] = rb1;
        *(float4*)&Bs[0][bkk[2]][bcol[2]] = rb2;
    }
    __syncthreads();

    for (int t = 0; t < 64; ++t) {
        const int cur = t & 1;
        if (t < 63) {   // prefetch next k-tile into registers
            const int k0 = (t + 1) << 4;
            ra  = *(const float4*)&x[axoff + k0];
            rb0 = *(const float4*)&bw[0][(k0 + bkk[0]) * NH];
            rb1 = *(const float4*)&bw[1][(k0 + bkk[1]) * NH];
            rb2 = *(const float4*)&bw[2][(k0 + bkk[2]) * NH];
        }
        #pragma unroll
        for (int kk = 0; kk < 16; ++kk) {
            const float4 av = *(const float4*)&As[cur][kk][tr];
            const float4 b0 = *(const float4*)&Bs[cur][kk][tc + 0];
            const float4 b1 = *(const float4*)&Bs[cur][kk][tc + 4];
            const float4 b2 = *(const float4*)&Bs[cur][kk][tc + 8];
            const float a[4]   = {av.x, av.y, av.z, av.w};
            const float bj[12] = {b0.x,b0.y,b0.z,b0.w,b1.x,b1.y,b1.z,b1.w,b2.x,b2.y,b2.z,b2.w};
            #pragma unroll
            for (int i = 0; i < 4; ++i)
                #pragma unroll
                for (int j = 0; j < 12; ++j)
                    acc[i][j] = fmaf(a[i], bj[j], acc[i][j]);
        }
        if (t < 63) {   // store prefetched regs into the other buffer
            const int nxt = cur ^ 1;
            const float rav[4] = {ra.x, ra.y, ra.z, ra.w};
            #pragma unroll
            for (int j = 0; j < 4; ++j) As[nxt][ak4 + j][arow] = rav[j];
            *(float4*)&Bs[nxt][bkk[0]][bcol[0]] = rb0;
            *(float4*)&Bs[nxt][bkk[1]][bcol[1]] = rb1;
            *(float4*)&Bs[nxt][bkk[2]][bcol[2]] = rb2;
        }
        __syncthreads();
    }

    #pragma unroll
    for (int i = 0; i < 4; ++i) {
        const int gr = m0 + tr + i;
        #pragma unroll
        for (int j = 0; j < 12; ++j) {
            const int n = tc + j;
            float* op = (n < 64) ? kb : ((n < 128) ? qb : vb);
            op[gr * NH + (n & 63)] = acc[i][j];
        }
    }
}

// ============ Sliding-window causal attention (flash-style) ============
// grid = (T/QT, B), 256 threads. Thread (qp=tid>>4, kg=tid&15):
//   QK phase: rows {2qp,2qp+1} x keys {kg+16j}; PV phase: same rows x dims kg*4..+3.
//   m/l/f online-softmax state kept redundantly in the 16 lanes of each row group.
__global__ __launch_bounds__(256)
void attn_swin(const float* __restrict__ qb,
               const float* __restrict__ kb,
               const float* __restrict__ vb,
               float* __restrict__ out)
{
    __shared__ float qs[QT][68];
    __shared__ float ks[KT][68];
    __shared__ float vs[KT][68];
    __shared__ float ps[QT][68];

    const int tid  = threadIdx.x;
    const int q0   = blockIdx.x * QT;
    const int base = blockIdx.y * TSEQ;

    // load q tile (32 x 64 fp32)
    #pragma unroll
    for (int i = 0; i < 2; ++i) {
        const int idx = tid + (i << 8);
        const int r = idx >> 4, c4 = (idx & 15) << 2;
        *(float4*)&qs[r][c4] = *(const float4*)&qb[(base + q0 + r) * NH + c4];
    }

    const int qp  = tid >> 4;
    const int kg  = tid & 15;
    const int qi0 = q0 + qp * 2;
    const int qi1 = qi0 + 1;

    float mr0 = -FLT_MAX, mr1 = -FLT_MAX;
    float l0 = 0.f, l1 = 0.f;
    float acc0[4] = {0.f,0.f,0.f,0.f};
    float acc1[4] = {0.f,0.f,0.f,0.f};

    int lo = q0 - (WIN - 1); if (lo < 0) lo = 0;
    const int t_lo = lo >> 6;
    const int t_hi = (q0 + QT - 1) >> 6;

    for (int t = t_lo; t <= t_hi; ++t) {
        const int k0 = t << 6;
        __syncthreads();    // protect ks/vs/ps from previous iteration readers
        #pragma unroll
        for (int i = 0; i < 4; ++i) {
            const int idx = tid + (i << 8);
            const int r = idx >> 4, c4 = (idx & 15) << 2;
            *(float4*)&ks[r][c4] = *(const float4*)&kb[(base + k0 + r) * NH + c4];
            *(float4*)&vs[r][c4] = *(const float4*)&vb[(base + k0 + r) * NH + c4];
        }
        __syncthreads();

        // ---- QK^T: 2 rows x 4 keys per thread (keys strided by 16 -> no LDS conflicts)
        float s0[4] = {0.f,0.f,0.f,0.f};
        float s1[4] = {0.f,0.f,0.f,0.f};
        #pragma unroll
        for (int cc = 0; cc < 16; ++cc) {
            const float4 qv0 = *(const float4*)&qs[qp*2+0][cc << 2];
            const float4 qv1 = *(const float4*)&qs[qp*2+1][cc << 2];
            #pragma unroll
            for (int j = 0; j < 4; ++j) {
                const float4 kv = *(const float4*)&ks[kg + (j << 4)][cc << 2];
                s0[j] = fmaf(qv0.x, kv.x, s0[j]); s0[j] = fmaf(qv0.y, kv.y, s0[j]);
                s0[j] = fmaf(qv0.z, kv.z, s0[j]); s0[j] = fmaf(qv0.w, kv.w, s0[j]);
                s1[j] = fmaf(qv1.x, kv.x, s1[j]); s1[j] = fmaf(qv1.y, kv.y, s1[j]);
                s1[j] = fmaf(qv1.z, kv.z, s1[j]); s1[j] = fmaf(qv1.w, kv.w, s1[j]);
            }
        }

        // ---- mask + online softmax
        float tm0 = -FLT_MAX, tm1 = -FLT_MAX;
        bool vld0[4], vld1[4];
        #pragma unroll
        for (int j = 0; j < 4; ++j) {
            const int kj = k0 + kg + (j << 4);
            s0[j] *= 0.125f; s1[j] *= 0.125f;
            vld0[j] = (kj <= qi0) && (kj > qi0 - WIN);
            vld1[j] = (kj <= qi1) && (kj > qi1 - WIN);
            if (vld0[j]) tm0 = fmaxf(tm0, s0[j]);
            if (vld1[j]) tm1 = fmaxf(tm1, s1[j]);
        }
        #pragma unroll
        for (int off = 8; off > 0; off >>= 1) {
            tm0 = fmaxf(tm0, __shfl_xor(tm0, off));
            tm1 = fmaxf(tm1, __shfl_xor(tm1, off));
        }
        const float mn0 = fmaxf(mr0, tm0);
        const float mn1 = fmaxf(mr1, tm1);
        const float f0 = __expf(mr0 - mn0);
        const float f1 = __expf(mr1 - mn1);
        float sum0 = 0.f, sum1 = 0.f;
        #pragma unroll
        for (int j = 0; j < 4; ++j) {
            const float p0 = vld0[j] ? __expf(s0[j] - mn0) : 0.f;
            const float p1 = vld1[j] ? __expf(s1[j] - mn1) : 0.f;
            sum0 += p0; sum1 += p1;
            ps[qp*2+0][kg + (j << 4)] = p0;
            ps[qp*2+1][kg + (j << 4)] = p1;
        }
        #pragma unroll
        for (int off = 8; off > 0; off >>= 1) {
            sum0 += __shfl_xor(sum0, off);
            sum1 += __shfl_xor(sum1, off);
        }
        l0 = l0 * f0 + sum0;
        l1 = l1 * f1 + sum1;
        mr0 = mn0; mr1 = mn1;
        __syncthreads();    // ps ready

        // ---- PV: same rows, dims kg*4..+3
        #pragma unroll
        for (int i = 0; i < 4; ++i) { acc0[i] *= f0; acc1[i] *= f1; }
        #pragma unroll
        for (int jc = 0; jc < 16; ++jc) {
            const float4 pa0 = *(const float4*)&ps[qp*2+0][jc << 2];
            const float4 pa1 = *(const float4*)&ps[qp*2+1][jc << 2];
            const float pv0[4] = {pa0.x, pa0.y, pa0.z, pa0.w};
            const float pv1[4] = {pa1.x, pa1.y, pa1.z, pa1.w};
            #pragma unroll
            for (int js = 0; js < 4; ++js) {
                const float4 vv = *(const float4*)&vs[(jc << 2) + js][kg << 2];
                acc0[0] = fmaf(pv0[js], vv.x, acc0[0]);
                acc0[1] = fmaf(pv0[js], vv.y, acc0[1]);
                acc0[2] = fmaf(pv0[js], vv.z, acc0[2]);
                acc0[3] = fmaf(pv0[js], vv.w, acc0[3]);
                acc1[0] = fmaf(pv1[js], vv.x, acc1[0]);
                acc1[1] = fmaf(pv1[js], vv.y, acc1[1]);
                acc1[2] = fmaf(pv1[js], vv.z, acc1[2]);
                acc1[3] = fmaf(pv1[js], vv.w, acc1[3]);
            }
        }
    }

    const float inv0 = 1.f / l0;
    const float inv1 = 1.f / l1;
    const float4 o0 = make_float4(acc0[0]*inv0, acc0[1]*inv0, acc0[2]*inv0, acc0[3]*inv0);
    const float4 o1 = make_float4(acc1[0]*inv1, acc1[1]*inv1, acc1[2]*inv1, acc1[3]*inv1);
    *(float4*)&out[(base + qi0) * NH + (kg << 2)] = o0;
    *(float4*)&out[(base + qi1) * NH + (kg << 2)] = o1;
}

extern "C" void kernel_launch(void* const* d_in, const int* in_sizes, int n_in,
                              void* d_out, int out_size, void* d_ws, size_t ws_size,
                              hipStream_t stream)
{
    const float* x  = (const float*)d_in[0];
    const float* Wk = (const float*)d_in[1];
    const float* Wq = (const float*)d_in[2];
    const float* Wv = (const float*)d_in[3];
    float* out = (float*)d_out;

    const int Bn = in_sizes[0] / (TSEQ * CEMB);   // batch (4)
    const size_t perBuf = (size_t)Bn * TSEQ * NH;

    float* kb = (float*)d_ws;
    float* qb = kb + perBuf;
    float* vb = qb + perBuf;

    const int Mtiles = (Bn * TSEQ) / 64;
    qkv_proj<<<dim3(Mtiles), dim3(256), 0, stream>>>(x, Wk, Wq, Wv, kb, qb, vb);
    attn_swin<<<dim3(TSEQ / QT, Bn), dim3(256), 0, stream>>>(qb, kb, vb, out);
}

// Round 4
// 153.493 us; speedup vs baseline: 1.5524x; 1.5524x over previous
//
#include <hip/hip_runtime.h>
#include <float.h>

#define TSEQ 4096
#define CEMB 1024
#define NH 64
#define WIN 256

typedef __attribute__((ext_vector_type(8))) short  s16x8;
typedef __attribute__((ext_vector_type(4))) short  s16x4;
typedef __attribute__((ext_vector_type(4))) float  f32x4;

// Truncation-based fp32 -> bf16 hi/lo split. |x - (hi+lo)| <= 2^-16 |x|.
__device__ __forceinline__ void split2(float f, short& hi, short& lo) {
    unsigned b = __float_as_uint(f);
    hi = (short)(b >> 16);
    float hf = __uint_as_float(b & 0xFFFF0000u);
    lo = (short)(__float_as_uint(f - hf) >> 16);
}

__device__ __forceinline__ void split8(f32x4 a, f32x4 b, s16x8& hi, s16x8& lo) {
    #pragma unroll
    for (int j = 0; j < 4; ++j) { short h, l; split2(a[j], h, l); hi[j] = h; lo[j] = l; }
    #pragma unroll
    for (int j = 0; j < 4; ++j) { short h, l; split2(b[j], h, l); hi[4+j] = h; lo[4+j] = l; }
}

#define MFMA(a, b, c) __builtin_amdgcn_mfma_f32_16x16x32_bf16((a), (b), (c), 0, 0, 0)

// ======================= W pre-convert: Wt[n][k] bf16 hi/lo =======================
// n in [0,192): 0-63 Wk cols, 64-127 Wq, 128-191 Wv.  grid 48 x 256.
__global__ __launch_bounds__(256)
void w_convert(const float* __restrict__ Wk, const float* __restrict__ Wq,
               const float* __restrict__ Wv,
               short* __restrict__ Wth, short* __restrict__ Wtl)
{
    const int m  = blockIdx.x >> 4;           // matrix 0..2
    const int k0 = (blockIdx.x & 15) << 6;    // k tile base
    const float* src = (m == 0) ? Wk : ((m == 1) ? Wq : Wv);
    #pragma unroll
    for (int i = 0; i < 16; ++i) {
        const int idx = threadIdx.x + (i << 8);
        const int r = idx >> 6, c = idx & 63;
        const float v = src[(k0 + r) * NH + c];
        short h, l; split2(v, h, l);
        const int o = (m * 64 + c) * CEMB + k0 + r;
        Wth[o] = h; Wtl[o] = l;
    }
}

// ======================= QKV projection via MFMA =======================
// Tile: 64 rows x 192 cols, K-step 32, double-buffered LDS, hi/lo bf16.
// LDS rows stride 32 shorts (64B), 16B-chunk XOR swizzle: chunk' = chunk ^ ((row>>1)&3).
__device__ __forceinline__ int swz(int row, int chunk) {
    return row * 32 + (((chunk) ^ ((row >> 1) & 3)) << 3);   // in shorts
}

__global__ __launch_bounds__(256)
void qkv_proj(const float* __restrict__ x,
              const short* __restrict__ Wth, const short* __restrict__ Wtl,
              float* __restrict__ kb, float* __restrict__ qb, float* __restrict__ vb)
{
    __shared__ short Ah[2][64 * 32], Al[2][64 * 32];
    __shared__ short Bh[2][192 * 32], Bl[2][192 * 32];

    const int tid = threadIdx.x;
    const int m0  = blockIdx.x << 6;
    const int w   = tid >> 6;
    const int l15 = tid & 15;
    const int g   = (tid >> 4) & 3;

    // x staging map: thread -> (row, k-chunk of 8)
    const int arow = tid >> 2;
    const int ach  = tid & 3;                  // chunk index (8 k each)
    const float* xp = x + (size_t)(m0 + arow) * CEMB + (ach << 3);

    // W staging map: 768 hi + 768 lo chunks; 3 of each per thread
    int wn[3], wch[3];
    #pragma unroll
    for (int i = 0; i < 3; ++i) {
        const int c = tid + (i << 8);
        wn[i] = c >> 2; wch[i] = c & 3;
    }

    f32x4 acc[4][3];
    #pragma unroll
    for (int i = 0; i < 4; ++i)
        #pragma unroll
        for (int j = 0; j < 3; ++j) acc[i][j] = (f32x4){0.f, 0.f, 0.f, 0.f};

    // prefetch tile 0
    f32x4 xr0 = *(const f32x4*)(xp);
    f32x4 xr1 = *(const f32x4*)(xp + 4);
    s16x8 wrh[3], wrl[3];
    #pragma unroll
    for (int i = 0; i < 3; ++i) {
        const int o = wn[i] * CEMB + (wch[i] << 3);
        wrh[i] = *(const s16x8*)&Wth[o];
        wrl[i] = *(const s16x8*)&Wtl[o];
    }

    for (int t = 0; t < 32; ++t) {
        const int cur = t & 1;
        // ---- write staged regs (tile t) into buf[cur]
        {
            s16x8 vh, vl; split8(xr0, xr1, vh, vl);
            const int ao = swz(arow, ach);
            *(s16x8*)&Ah[cur][ao] = vh;
            *(s16x8*)&Al[cur][ao] = vl;
            #pragma unroll
            for (int i = 0; i < 3; ++i) {
                const int bo = swz(wn[i], wch[i]);
                *(s16x8*)&Bh[cur][bo] = wrh[i];
                *(s16x8*)&Bl[cur][bo] = wrl[i];
            }
        }
        __syncthreads();
        // ---- prefetch tile t+1
        if (t < 31) {
            const int k0 = (t + 1) << 5;
            xr0 = *(const f32x4*)(xp + k0);
            xr1 = *(const f32x4*)(xp + k0 + 4);
            #pragma unroll
            for (int i = 0; i < 3; ++i) {
                const int o = wn[i] * CEMB + k0 + (wch[i] << 3);
                wrh[i] = *(const s16x8*)&Wth[o];
                wrl[i] = *(const s16x8*)&Wtl[o];
            }
        }
        // ---- fragments + MFMA
        s16x8 afh[4], afl[4], bfh[3], bfl[3];
        #pragma unroll
        for (int rt = 0; rt < 4; ++rt) {
            const int o = swz(rt * 16 + l15, g);
            afh[rt] = *(const s16x8*)&Ah[cur][o];
            afl[rt] = *(const s16x8*)&Al[cur][o];
        }
        #pragma unroll
        for (int ct = 0; ct < 3; ++ct) {
            const int n = w * 48 + ct * 16 + l15;
            const int o = swz(n, g);
            bfh[ct] = *(const s16x8*)&Bh[cur][o];
            bfl[ct] = *(const s16x8*)&Bl[cur][o];
        }
        #pragma unroll
        for (int rt = 0; rt < 4; ++rt)
            #pragma unroll
            for (int ct = 0; ct < 3; ++ct) {
                acc[rt][ct] = MFMA(afh[rt], bfh[ct], acc[rt][ct]);
                acc[rt][ct] = MFMA(afh[rt], bfl[ct], acc[rt][ct]);
                acc[rt][ct] = MFMA(afl[rt], bfh[ct], acc[rt][ct]);
            }
    }

    // ---- epilogue: C/D layout row = g*4+reg, col = l15 (within 16-tile)
    #pragma unroll
    for (int ct = 0; ct < 3; ++ct) {
        const int colbase = w * 48 + ct * 16;
        float* op = (colbase < 64) ? kb : ((colbase < 128) ? qb : vb);
        const int col = (colbase & 63) + l15;
        #pragma unroll
        for (int rt = 0; rt < 4; ++rt)
            #pragma unroll
            for (int r = 0; r < 4; ++r) {
                const int row = m0 + rt * 16 + g * 4 + r;
                op[(size_t)row * NH + col] = acc[rt][ct][r];
            }
    }
}

// ======================= Sliding-window attention via MFMA =======================
// Q-tile 64 (4 waves x 16 rows), K-tile 64. Swapped QK: S^T = K * Q^T so each
// lane owns one q-row's scores (col = lane&15). Hi/lo bf16 everywhere.
__global__ __launch_bounds__(256)
void attn_swin(const float* __restrict__ qb, const float* __restrict__ kb,
               const float* __restrict__ vb, float* __restrict__ out)
{
    __shared__ short Kh[64 * 72], Kl[64 * 72];        // [key][dim], stride 72
    __shared__ short Vth[64 * 72], Vtl[64 * 72];      // [dim][key], stride 72
    __shared__ short Ph[4][16 * 72], Pl[4][16 * 72];  // per-wave [qrow][key]

    const int tid = threadIdx.x;
    const int Q0  = blockIdx.x << 6;
    const size_t base = (size_t)blockIdx.y * TSEQ;
    const int w   = tid >> 6;
    const int l15 = tid & 15;
    const int g   = (tid >> 4) & 3;

    const int qrow = Q0 + w * 16 + l15;   // the q-row this lane owns (B-col)

    // Q B-fragments in registers: k = dim = ks*32 + g*8 + i
    s16x8 Qh[2], Ql[2];
    #pragma unroll
    for (int ks = 0; ks < 2; ++ks) {
        const float* qp = qb + (base + qrow) * NH + ks * 32 + g * 8;
        f32x4 a = *(const f32x4*)qp;
        f32x4 b = *(const f32x4*)(qp + 4);
        split8(a, b, Qh[ks], Ql[ks]);
    }

    f32x4 O[4];
    #pragma unroll
    for (int i = 0; i < 4; ++i) O[i] = (f32x4){0.f, 0.f, 0.f, 0.f};
    float m_run = -FLT_MAX, l_run = 0.f;

    int lo = Q0 - (WIN - 1); if (lo < 0) lo = 0;
    const int t_lo = lo >> 6, t_hi = Q0 >> 6;

    for (int t = t_lo; t <= t_hi; ++t) {
        const int k0 = t << 6;
        __syncthreads();   // previous tile's K/V reads complete
        // ---- stage K [key][dim]
        #pragma unroll
        for (int i = 0; i < 4; ++i) {
            const int idx = tid + (i << 8);
            const int key = idx >> 4, c4 = (idx & 15) << 2;
            f32x4 kv = *(const f32x4*)&kb[(base + k0 + key) * NH + c4];
            s16x4 h, l;
            #pragma unroll
            for (int j = 0; j < 4; ++j) { short hh, ll; split2(kv[j], hh, ll); h[j] = hh; l[j] = ll; }
            *(s16x4*)&Kh[key * 72 + c4] = h;
            *(s16x4*)&Kl[key * 72 + c4] = l;
        }
        // ---- stage V transposed [dim][key] via column-ordered coalesced loads
        #pragma unroll
        for (int i = 0; i < 2; ++i) {
            const int item = tid + (i << 8);
            const int dim = item & 63, kb8 = (item >> 6) << 3;
            f32x4 v0, v1;
            #pragma unroll
            for (int kk = 0; kk < 4; ++kk)
                v0[kk] = vb[(base + k0 + kb8 + kk) * NH + dim];
            #pragma unroll
            for (int kk = 0; kk < 4; ++kk)
                v1[kk] = vb[(base + k0 + kb8 + 4 + kk) * NH + dim];
            s16x8 h, l; split8(v0, v1, h, l);
            *(s16x8*)&Vth[dim * 72 + kb8] = h;
            *(s16x8*)&Vtl[dim * 72 + kb8] = l;
        }
        __syncthreads();

        // ---- S^T = K * Q^T : A-frag from K rows, B-frag = Q regs
        f32x4 S[4];
        #pragma unroll
        for (int kt = 0; kt < 4; ++kt) {
            f32x4 s = (f32x4){0.f, 0.f, 0.f, 0.f};
            #pragma unroll
            for (int ks = 0; ks < 2; ++ks) {
                const int o = (kt * 16 + l15) * 72 + ks * 32 + g * 8;
                s16x8 kah = *(const s16x8*)&Kh[o];
                s16x8 kal = *(const s16x8*)&Kl[o];
                s = MFMA(kah, Qh[ks], s);
                s = MFMA(kah, Ql[ks], s);
                s = MFMA(kal, Qh[ks], s);
            }
            S[kt] = s;
        }

        // ---- mask + online softmax (lane-local rows: key = k0 + kt*16 + g*4 + r)
        float sv[16]; bool vd[16];
        float mt = -FLT_MAX;
        #pragma unroll
        for (int kt = 0; kt < 4; ++kt)
            #pragma unroll
            for (int r = 0; r < 4; ++r) {
                const int key = k0 + kt * 16 + g * 4 + r;
                const float s = S[kt][r] * 0.125f;
                const bool v = (key <= qrow) && (key > qrow - WIN);
                sv[kt * 4 + r] = s; vd[kt * 4 + r] = v;
                if (v) mt = fmaxf(mt, s);
            }
        mt = fmaxf(mt, __shfl_xor(mt, 16));
        mt = fmaxf(mt, __shfl_xor(mt, 32));
        const float mn  = fmaxf(m_run, mt);
        const float fsc = __expf(m_run - mn);
        float sum = 0.f;
        #pragma unroll
        for (int kt = 0; kt < 4; ++kt)
            #pragma unroll
            for (int r = 0; r < 4; ++r) {
                const float p = vd[kt * 4 + r] ? __expf(sv[kt * 4 + r] - mn) : 0.f;
                sum += p;
                short h, l; split2(p, h, l);
                const int pc = kt * 16 + g * 4 + r;
                Ph[w][l15 * 72 + pc] = h;
                Pl[w][l15 * 72 + pc] = l;
            }
        sum += __shfl_xor(sum, 16);
        sum += __shfl_xor(sum, 32);
        l_run = l_run * fsc + sum;
        m_run = mn;

        // ---- rescale O (O rows are g*4+r; factors live in lanes 0-15)
        float fr[4];
        #pragma unroll
        for (int r = 0; r < 4; ++r) fr[r] = __shfl(fsc, g * 4 + r);
        #pragma unroll
        for (int dt = 0; dt < 4; ++dt)
            #pragma unroll
            for (int r = 0; r < 4; ++r) O[dt][r] *= fr[r];

        // ---- O += P * V  (A = P rows from LDS, B = V^T rows)
        #pragma unroll
        for (int ks = 0; ks < 2; ++ks) {
            const int po = l15 * 72 + ks * 32 + g * 8;
            s16x8 pah = *(const s16x8*)&Ph[w][po];
            s16x8 pal = *(const s16x8*)&Pl[w][po];
            #pragma unroll
            for (int dt = 0; dt < 4; ++dt) {
                const int vo = (dt * 16 + l15) * 72 + ks * 32 + g * 8;
                s16x8 vbh = *(const s16x8*)&Vth[vo];
                s16x8 vbl = *(const s16x8*)&Vtl[vo];
                O[dt] = MFMA(pah, vbh, O[dt]);
                O[dt] = MFMA(pah, vbl, O[dt]);
                O[dt] = MFMA(pal, vbh, O[dt]);
            }
        }
    }

    // ---- epilogue: normalize rows and store
    const float linv = 1.f / l_run;
    float fr[4];
    #pragma unroll
    for (int r = 0; r < 4; ++r) fr[r] = __shfl(linv, g * 4 + r);
    #pragma unroll
    for (int dt = 0; dt < 4; ++dt)
        #pragma unroll
        for (int r = 0; r < 4; ++r) {
            const int row = Q0 + w * 16 + g * 4 + r;
            out[(base + row) * NH + dt * 16 + l15] = O[dt][r] * fr[r];
        }
}

extern "C" void kernel_launch(void* const* d_in, const int* in_sizes, int n_in,
                              void* d_out, int out_size, void* d_ws, size_t ws_size,
                              hipStream_t stream)
{
    const float* x  = (const float*)d_in[0];
    const float* Wk = (const float*)d_in[1];
    const float* Wq = (const float*)d_in[2];
    const float* Wv = (const float*)d_in[3];
    float* out = (float*)d_out;

    const int Bn = in_sizes[0] / (TSEQ * CEMB);
    const size_t perBuf = (size_t)Bn * TSEQ * NH;

    float* kb = (float*)d_ws;
    float* qb = kb + perBuf;
    float* vb = qb + perBuf;
    short* Wth = (short*)(vb + perBuf);
    short* Wtl = Wth + 192 * CEMB;

    w_convert<<<dim3(48), dim3(256), 0, stream>>>(Wk, Wq, Wv, Wth, Wtl);
    qkv_proj<<<dim3((Bn * TSEQ) / 64), dim3(256), 0, stream>>>(x, Wth, Wtl, kb, qb, vb);
    attn_swin<<<dim3(TSEQ / 64, Bn), dim3(256), 0, stream>>>(qb, kb, vb, out);
}